// Round 1
// 768.439 us; speedup vs baseline: 1.0718x; 1.0718x over previous
//
#include <hip/hip_runtime.h>
#include <cmath>

// Problem constants
#define CN   256   // channels (N_DIST)
#define HN   256   // H
#define WN   192   // W
#define KN   129   // kernel taps
#define RN   64    // radius
#define SN   256   // padded size
#define PADN 32    // (SN - WN)/2

// Rotation LDS tile: 64x64 output tile -> rotated source bbox <= 91x91
// (64*(|c|+|s|) + floor/ulp margins). 92 rows x 96 pitch = 35.3 KB -> 4 blk/CU.
#define BBR 92
#define BBP 96

// ================= conv along W (last axis), 4-stage LDS =================
// Block: 256 thr = 4 waves. Tile: 64 rows x 64 output cols; lane = row.
// Taps in 4 stages of 32 (+1); stage slab = 64 x 96 window cols in LDS
// (pitch 97, odd => lane-strided b32 conflict-free; 25.4 KB).
// Inner loop: groups of 4 taps on three 16-reg half-buffers; H2's 16
// ds_reads issue ~3 q-blocks (~380 issue-cycles) before first use.
template <int WD, bool ACC>
__global__ __launch_bounds__(256, 5) void conv_w_lds(const float* __restrict__ in,
                                                     const float* __restrict__ kern,
                                                     float* __restrict__ out) {
    constexpr int PITCH = 97;
    __shared__ float lds[64 * PITCH + 132];
    float* __restrict__ ldsK = lds + 64 * PITCH;
    const int tid = threadIdx.x;
    const int x0  = blockIdx.x * 64;
    const int h0  = blockIdx.y * 64;
    const int c   = blockIdx.z;
    const float* __restrict__ in_c = in + ((size_t)c * HN + h0) * WD;

    if (tid < 132) ldsK[tid] = (tid < KN) ? kern[c * KN + tid] : 0.f;

    const int wv = tid >> 6;            // wave -> output col chunk
    const int l  = tid & 63;            // lane = row
    const int base  = l * PITCH + wv * 16;
    const int col32 = tid & 31;         // staging decomposition
    const int r8    = tid >> 5;         // 0..7

    float acc[16];
#pragma unroll
    for (int t = 0; t < 16; ++t) acc[t] = 0.f;

#pragma unroll 1
    for (int s = 0; s < 4; ++s) {
        __syncthreads();                // prior stage reads done
        const int off = x0 + 32 * s - 64;   // global col of slab col 0
        if (off >= 0 && off + 96 <= WD) {   // interior: no bounds code
#pragma unroll
            for (int m = 0; m < 3; ++m)
#pragma unroll
                for (int k = 0; k < 8; ++k)
                    lds[(r8 + 8 * k) * PITCH + col32 + 32 * m] =
                        in_c[(size_t)(r8 + 8 * k) * WD + off + col32 + 32 * m];
        } else {
#pragma unroll
            for (int m = 0; m < 3; ++m)
#pragma unroll
                for (int k = 0; k < 8; ++k) {
                    int g  = off + col32 + 32 * m;
                    int gc = min(max(g, 0), WD - 1);
                    float v = in_c[(size_t)(r8 + 8 * k) * WD + gc];
                    lds[(r8 + 8 * k) * PITCH + col32 + 32 * m] = (g == gc) ? v : 0.f;
                }
        }
        __syncthreads();

        float H0[16], H1[16], H2[16];
#pragma unroll
        for (int i = 0; i < 16; ++i) H0[i] = lds[base + i];
#pragma unroll
        for (int i = 0; i < 16; ++i) H1[i] = lds[base + 16 + i];

        const float4* __restrict__ k4 = (const float4*)ldsK;
        float4 kc = k4[8 * s];
#pragma unroll
        for (int q = 0; q < 8; ++q) {       // 4 taps per q, 32 taps/stage
            float4 kn = (q < 7) ? k4[8 * s + q + 1] : kc;
#pragma unroll
            for (int u = 0; u < 4; ++u) {
                const int up = 4 * q + u;
                const float kj = (u == 0) ? kc.x : (u == 1) ? kc.y
                               : (u == 2) ? kc.z : kc.w;
#pragma unroll
                for (int t = 0; t < 16; ++t) {
                    const int e = up + t;   // compile-time after unroll
                    const float val = (e < 16) ? H0[e]
                                    : (e < 32) ? H1[e - 16] : H2[e - 32];
                    acc[t] = fmaf(val, kj, acc[t]);
                }
            }
            if (q == 0) {                   // prefetch H2: consumed from q=4
#pragma unroll
                for (int i = 0; i < 16; ++i) H2[i] = lds[base + 32 + i];
            }
            kc = kn;
        }
        if (s == 3) {                       // tap 128 uses H2 exactly
            const float k128 = ldsK[128];
#pragma unroll
            for (int t = 0; t < 16; ++t) acc[t] = fmaf(H2[t], k128, acc[t]);
        }
    }

    float4* __restrict__ o4 =
        (float4*)(out + ((size_t)c * HN + h0 + l) * WD + x0 + wv * 16);
#pragma unroll
    for (int q = 0; q < 4; ++q) {
        float4 v;
        v.x = acc[4*q]; v.y = acc[4*q+1]; v.z = acc[4*q+2]; v.w = acc[4*q+3];
        if (ACC) {
            float4 o = o4[q];
            v.x += o.x; v.y += o.y; v.z += o.z; v.w += o.w;
        }
        o4[q] = v;
    }
}

// ================= conv along H (axis 1), 4-stage LDS =================
// Block: 256 thr = 4 waves. Tile: 64 output rows x 64 cols; lane = col.
// Stage s stages slab rows [32s-64+h0, +96) x 64 cols (24.6 KB, pitch 64,
// lane-consecutive = conflict-free). Same 3-half-buffer inner loop as conv_w.
__global__ __launch_bounds__(256, 5) void conv_h_lds(const float* __restrict__ in,
                                                     const float* __restrict__ kern,
                                                     float* __restrict__ out) {
    __shared__ float lds[96 * 64 + 132];
    float* __restrict__ ldsK = lds + 96 * 64;
    const int tid = threadIdx.x;
    const int x0  = blockIdx.x * 64;
    const int h0  = blockIdx.y * 64;
    const int c   = blockIdx.z;
    const float* __restrict__ in_c = in + (size_t)c * HN * WN + x0;

    if (tid < 132) ldsK[tid] = (tid < KN) ? kern[c * KN + tid] : 0.f;

    const int wv = tid >> 6;            // wave -> output row chunk
    const int l  = tid & 63;            // lane = col
    const int baseRow = wv * 16;        // slab row of window element 0
    const int col = tid & 63;           // staging: lane-coalesced
    const int r4  = tid >> 6;           // 0..3; rows r4 + 4k

    float acc[16];
#pragma unroll
    for (int t = 0; t < 16; ++t) acc[t] = 0.f;

#pragma unroll 1
    for (int s = 0; s < 4; ++s) {
        __syncthreads();                // prior stage reads done
        const int off = h0 + 32 * s - 64;   // global row of slab row 0
        if (off >= 0 && off + 96 <= HN) {   // interior fast path
#pragma unroll
            for (int k = 0; k < 24; ++k)
                lds[(r4 + 4 * k) * 64 + col] =
                    in_c[(size_t)(off + r4 + 4 * k) * WN + col];
        } else {
#pragma unroll
            for (int k = 0; k < 24; ++k) {
                int g  = off + r4 + 4 * k;
                int gc = min(max(g, 0), HN - 1);
                float v = in_c[(size_t)gc * WN + col];
                lds[(r4 + 4 * k) * 64 + col] = (g == gc) ? v : 0.f;
            }
        }
        __syncthreads();

        float H0[16], H1[16], H2[16];
#pragma unroll
        for (int i = 0; i < 16; ++i) H0[i] = lds[(baseRow + i) * 64 + l];
#pragma unroll
        for (int i = 0; i < 16; ++i) H1[i] = lds[(baseRow + 16 + i) * 64 + l];

        const float4* __restrict__ k4 = (const float4*)ldsK;
        float4 kc = k4[8 * s];
#pragma unroll
        for (int q = 0; q < 8; ++q) {       // 4 taps per q, 32 taps/stage
            float4 kn = (q < 7) ? k4[8 * s + q + 1] : kc;
#pragma unroll
            for (int u = 0; u < 4; ++u) {
                const int up = 4 * q + u;
                const float kj = (u == 0) ? kc.x : (u == 1) ? kc.y
                               : (u == 2) ? kc.z : kc.w;
#pragma unroll
                for (int t = 0; t < 16; ++t) {
                    const int e = up + t;
                    const float val = (e < 16) ? H0[e]
                                    : (e < 32) ? H1[e - 16] : H2[e - 32];
                    acc[t] = fmaf(val, kj, acc[t]);
                }
            }
            if (q == 0) {                   // prefetch H2: consumed from q=4
#pragma unroll
                for (int i = 0; i < 16; ++i)
                    H2[i] = lds[(baseRow + 32 + i) * 64 + l];
            }
            kc = kn;
        }
        if (s == 3) {                       // tap 128 uses H2 exactly
            const float k128 = ldsK[128];
#pragma unroll
            for (int t = 0; t < 16; ++t) acc[t] = fmaf(H2[t], k128, acc[t]);
        }
    }

    float* __restrict__ ob = out + ((size_t)c * HN + h0 + wv * 16) * WN + x0 + l;
#pragma unroll
    for (int t = 0; t < 16; ++t) ob[(size_t)t * WN] = acc[t];
}

// ---------------- forward rotate via LDS tile ----------------
// 64x64 output tile per block; rotated source bbox (<=91x91, +-1 ulp margin)
// staged COALESCED into LDS, zero-extended (bilinear w/ per-corner validity
// == bilinear on zero-extended plane, value-identical). Gather = 2x
// ds_read2_b32 per output; lane addr stride ~83 dwords -> bank stride 19/20
// mod 32, near conflict-free. Writes: wave = one 64-wide row, coalesced.
__global__ __launch_bounds__(256) void rot_fwd_lds(const float* __restrict__ Cin,
                                                   float* __restrict__ out,
                                                   float ca, float sa) {
    __shared__ float tile[BBR * BBP];
    const int j0 = blockIdx.x * 64;
    const int i0 = blockIdx.y * 64;
    const int c  = blockIdx.z;
    const float cc = (SN - 1) * 0.5f;               // 127.5
    // bbox of sample positions: affine in (i,j) -> extremes at tile corners
    const float yA = (float)i0 - cc, yB = (float)(i0 + 63) - cc;
    const float xA = (float)j0 - cc, xB = (float)(j0 + 63) - cc;
    const float syAA = ca * yA + sa * xA + cc, syAB = ca * yA + sa * xB + cc;
    const float syBA = ca * yB + sa * xA + cc, syBB = ca * yB + sa * xB + cc;
    const float sxAA = -sa * yA + ca * xA + cc, sxAB = -sa * yA + ca * xB + cc;
    const float sxBA = -sa * yB + ca * xA + cc, sxBB = -sa * yB + ca * xB + cc;
    const int ybase = (int)floorf(fminf(fminf(syAA, syAB), fminf(syBA, syBB))) - 1;
    const int xbase = (int)floorf(fminf(fminf(sxAA, sxAB), fminf(sxBA, sxBB))) - 1;

    const float* __restrict__ base = Cin + (size_t)c * HN * WN;
    for (int t = threadIdx.x; t < BBR * BBP; t += 256) {
        const int r  = t / BBP;
        const int q  = t - r * BBP;
        const int gy = ybase + r;           // padded-space row == C row
        const int gx = xbase + q - PADN;    // col into C (implicit zero pad)
        float v = 0.f;
        if ((unsigned)gy < (unsigned)HN && (unsigned)gx < (unsigned)WN)
            v = base[(size_t)gy * WN + gx];
        tile[t] = v;
    }
    __syncthreads();

    const int l  = threadIdx.x & 63;        // col within tile (lane)
    const int r0 = threadIdx.x >> 6;        // wave -> row phase
    const int j  = j0 + l;
    const float xx = (float)j - cc;
    float* __restrict__ ocol = out + (size_t)c * SN * SN + j;
#pragma unroll
    for (int t = 0; t < 16; ++t) {
        const int i = i0 + r0 + 4 * t;
        const float yy = (float)i - cc;
        const float sy = ca * yy + sa * xx + cc;
        const float sx = -sa * yy + ca * xx + cc;
        const float y0f = floorf(sy), x0f = floorf(sx);
        const float fy = sy - y0f, fx = sx - x0f;
        const int ly = (int)y0f - ybase;
        const int lx = (int)x0f - xbase;
        const float* p = tile + ly * BBP + lx;
        const float v00 = p[0], v01 = p[1], v10 = p[BBP], v11 = p[BBP + 1];
        ocol[(size_t)i * SN] = (1.f - fy) * ((1.f - fx) * v00 + fx * v01)
                             + fy * ((1.f - fx) * v10 + fx * v11);
    }
}

// ---------------- inverse rotate via LDS tile (+ optional fused finalize) ----
// Same structure; source = U (256x256, zero-extended), output 64x64 tile of
// the cropped 256x192 image. FINAL: dst = C (d_out) in place,
// out = (C + acc + tail2) / norm[c]  -- replaces final_k.
template <bool FINAL>
__global__ __launch_bounds__(256) void rot_bwd_lds(const float* __restrict__ U,
                                                   float* __restrict__ dst,
                                                   const float* __restrict__ accIn,
                                                   const float* __restrict__ norm,
                                                   float ca, float sa) {
    __shared__ float tile[BBR * BBP];
    const int x0 = blockIdx.x * 64;
    const int i0 = blockIdx.y * 64;
    const int c  = blockIdx.z;
    const float cc = (SN - 1) * 0.5f;
    const float yA = (float)i0 - cc, yB = (float)(i0 + 63) - cc;
    const float xA = (float)(x0 + PADN) - cc, xB = (float)(x0 + PADN + 63) - cc;
    const float syAA = ca * yA + sa * xA + cc, syAB = ca * yA + sa * xB + cc;
    const float syBA = ca * yB + sa * xA + cc, syBB = ca * yB + sa * xB + cc;
    const float sxAA = -sa * yA + ca * xA + cc, sxAB = -sa * yA + ca * xB + cc;
    const float sxBA = -sa * yB + ca * xA + cc, sxBB = -sa * yB + ca * xB + cc;
    const int ybase = (int)floorf(fminf(fminf(syAA, syAB), fminf(syBA, syBB))) - 1;
    const int xbase = (int)floorf(fminf(fminf(sxAA, sxAB), fminf(sxBA, sxBB))) - 1;

    const float* __restrict__ base = U + (size_t)c * SN * SN;
    for (int t = threadIdx.x; t < BBR * BBP; t += 256) {
        const int r  = t / BBP;
        const int q  = t - r * BBP;
        const int gy = ybase + r;
        const int gx = xbase + q;
        float v = 0.f;
        if ((unsigned)gy < (unsigned)SN && (unsigned)gx < (unsigned)SN)
            v = base[(size_t)gy * SN + gx];
        tile[t] = v;
    }
    __syncthreads();

    const int l  = threadIdx.x & 63;
    const int r0 = threadIdx.x >> 6;
    const int xc = x0 + l;
    const float xx = (float)(xc + PADN) - cc;
    float inv = 0.f;
    if constexpr (FINAL) inv = 1.f / norm[c];
#pragma unroll
    for (int t = 0; t < 16; ++t) {
        const int i = i0 + r0 + 4 * t;
        const float yy = (float)i - cc;
        const float sy = ca * yy + sa * xx + cc;
        const float sx = -sa * yy + ca * xx + cc;
        const float y0f = floorf(sy), x0f = floorf(sx);
        const float fy = sy - y0f, fx = sx - x0f;
        const int ly = (int)y0f - ybase;
        const int lx = (int)x0f - xbase;
        const float* p = tile + ly * BBP + lx;
        const float v00 = p[0], v01 = p[1], v10 = p[BBP], v11 = p[BBP + 1];
        const float val = (1.f - fy) * ((1.f - fx) * v00 + fx * v01)
                        + fy * ((1.f - fx) * v10 + fx * v11);
        const size_t idx = ((size_t)c * HN + i) * WN + xc;
        if constexpr (FINAL) {
            dst[idx] = (dst[idx] + accIn[idx] + val) * inv;
        } else {
            dst[idx] += val;
        }
    }
}

extern "C" void kernel_launch(void* const* d_in, const int* in_sizes, int n_in,
                              void* d_out, int out_size, void* d_ws, size_t ws_size,
                              hipStream_t stream) {
    const float* x    = (const float*)d_in[0];
    const float* kg   = (const float*)d_in[1];
    const float* kw   = (const float*)d_in[2];
    const float* kiso = (const float*)d_in[3];
    const float* norm = (const float*)d_in[4];

    float* C = (float*)d_out;                 // 256*256*192 floats
    float* ws = (float*)d_ws;
    const size_t IMG = (size_t)CN * HN * WN;  // 12,582,912
    const size_t PSQ = (size_t)CN * SN * SN;  // 16,777,216
    float* B   = ws;                          // IMG
    float* acc = ws + IMG;                    // IMG
    float* T   = ws + 2 * IMG;                // PSQ
    float* U   = T + PSQ;                     // PSQ

    const dim3 blk256(256);
    const dim3 convHGrid(WN / 64, HN / 64, CN);
    const dim3 convW192Grid(WN / 64, HN / 64, CN);
    const dim3 convW256Grid(SN / 64, HN / 64, CN);
    const dim3 rotFGrid(SN / 64, SN / 64, CN);   // 4 x 4 x 256
    const dim3 rotBGrid(WN / 64, HN / 64, CN);   // 3 x 4 x 256

    // 1-2: gaussian separable conv -> C (d_out)
    conv_h_lds<<<convHGrid, blk256, 0, stream>>>(x, kg, B);
    conv_w_lds<WN, false><<<convW192Grid, blk256, 0, stream>>>(B, kg, C);
    // 3-4: iso separable conv -> acc
    conv_h_lds<<<convHGrid, blk256, 0, stream>>>(C, kiso, B);
    conv_w_lds<WN, false><<<convW192Grid, blk256, 0, stream>>>(B, kiso, acc);
    // 5: i=0 tail term (identity rotation): acc += conv_w(C, kw)
    conv_w_lds<WN, true><<<convW192Grid, blk256, 0, stream>>>(C, kw, acc);
    // 6-11: i=1,2 tail terms
    const double a1 = 60.0 * M_PI / 180.0, a2 = 120.0 * M_PI / 180.0;
    const float c1 = (float)cos(a1), s1 = (float)sin(a1);
    const float c2 = (float)cos(a2), s2 = (float)sin(a2);

    rot_fwd_lds<<<rotFGrid, blk256, 0, stream>>>(C, T, c1, s1);
    conv_w_lds<SN, false><<<convW256Grid, blk256, 0, stream>>>(T, kw, U);
    rot_bwd_lds<false><<<rotBGrid, blk256, 0, stream>>>(U, acc, nullptr, nullptr, c1, -s1);

    rot_fwd_lds<<<rotFGrid, blk256, 0, stream>>>(C, T, c2, s2);
    conv_w_lds<SN, false><<<convW256Grid, blk256, 0, stream>>>(T, kw, U);
    // 12 fused: out = (C + acc + tail2) / norm[c]
    rot_bwd_lds<true><<<rotBGrid, blk256, 0, stream>>>(U, C, acc, norm, c2, -s2);

    (void)in_sizes; (void)n_in; (void)out_size; (void)ws_size;
}

// Round 2
// 761.999 us; speedup vs baseline: 1.0808x; 1.0085x over previous
//
#include <hip/hip_runtime.h>
#include <cmath>

// Problem constants
#define CN   256   // channels (N_DIST)
#define HN   256   // H
#define WN   192   // W
#define KN   129   // kernel taps
#define RN   64    // radius
#define SN   256   // padded size
#define PADN 32    // (SN - WN)/2

// Rotation LDS tile: 64x64 output tile -> rotated source bbox <= 91x91
// (64*(|c|+|s|) + floor/ulp margins). 92 rows x 96 pitch = 35.3 KB -> 4 blk/CU.
#define BBR 92
#define BBP 96

// ================= conv along W (last axis), single-stage LDS =================
// Block: 512 thr = 8 waves. Tile: 64 rows x 64 output cols; lane = row,
// wave = 8-col output chunk. Full 64x192 window staged ONCE (pitch 193, odd
// => lane-strided b32 reads conflict-free; 48.8 KB -> 3 blocks/CU = 24 waves).
// Inner loop: 4 stages of 32 taps on five 8-reg rolling buffers; B4's 8
// ds_reads issue at q=0, first consumed at q=6. Stores transposed through
// LDS so each wave writes 256 B contiguous (full-line HBM writes).
template <int WD, bool ACC>
__global__ __launch_bounds__(512, 6) void conv_w_lds(const float* __restrict__ in,
                                                     const float* __restrict__ kern,
                                                     float* __restrict__ out) {
    constexpr int PITCH = 193;
    __shared__ float lds[64 * PITCH + 132];
    float* __restrict__ ldsK = lds + 64 * PITCH;
    const int tid = threadIdx.x;
    const int x0  = blockIdx.x * 64;
    const int h0  = blockIdx.y * 64;
    const int c   = blockIdx.z;
    const float* __restrict__ in_c = in + ((size_t)c * HN + h0) * WD;

    if (tid < 132) ldsK[tid] = (tid < KN) ? kern[c * KN + tid] : 0.f;

    const int wv = tid >> 6;            // wave -> 8-col output chunk
    const int l  = tid & 63;            // lane = row
    const int base  = l * PITCH + wv * 8;
    const int col64 = tid & 63;         // staging: lane-coalesced cols
    const int r8    = tid >> 6;         // 0..7; rows r8 + 8k

    // ---- stage the full 64 x 192 window once: cols [x0-64, x0+128) ----
    const int off = x0 - 64;
    if (off >= 0 && off + 192 <= WD) {  // interior: no bounds code
#pragma unroll
        for (int m = 0; m < 3; ++m)
#pragma unroll
            for (int k = 0; k < 8; ++k)
                lds[(r8 + 8 * k) * PITCH + col64 + 64 * m] =
                    in_c[(size_t)(r8 + 8 * k) * WD + off + col64 + 64 * m];
    } else {
#pragma unroll
        for (int m = 0; m < 3; ++m)
#pragma unroll
            for (int k = 0; k < 8; ++k) {
                int g  = off + col64 + 64 * m;
                int gc = min(max(g, 0), WD - 1);
                float v = in_c[(size_t)(r8 + 8 * k) * WD + gc];
                lds[(r8 + 8 * k) * PITCH + col64 + 64 * m] = (g == gc) ? v : 0.f;
            }
    }
    __syncthreads();

    float acc[8];
#pragma unroll
    for (int t = 0; t < 8; ++t) acc[t] = 0.f;

    float B0[8], B1[8], B2[8], B3[8], B4[8];
    const float4* __restrict__ k4 = (const float4*)ldsK;
#pragma unroll
    for (int s = 0; s < 4; ++s) {
        const int sb = base + 32 * s;
#pragma unroll
        for (int i = 0; i < 8; ++i) B0[i] = lds[sb + i];
#pragma unroll
        for (int i = 0; i < 8; ++i) B1[i] = lds[sb + 8 + i];
#pragma unroll
        for (int i = 0; i < 8; ++i) B2[i] = lds[sb + 16 + i];
#pragma unroll
        for (int i = 0; i < 8; ++i) B3[i] = lds[sb + 24 + i];
        float4 kc = k4[8 * s];
#pragma unroll
        for (int q = 0; q < 8; ++q) {       // 4 taps per q, 32 taps/stage
            float4 kn = (q < 7) ? k4[8 * s + q + 1] : kc;
#pragma unroll
            for (int u = 0; u < 4; ++u) {
                const int up = 4 * q + u;
                const float kj = (u == 0) ? kc.x : (u == 1) ? kc.y
                               : (u == 2) ? kc.z : kc.w;
#pragma unroll
                for (int t = 0; t < 8; ++t) {
                    const int e = up + t;   // compile-time after unroll
                    const float val = (e < 8)  ? B0[e]
                                    : (e < 16) ? B1[e - 8]
                                    : (e < 24) ? B2[e - 16]
                                    : (e < 32) ? B3[e - 24] : B4[e - 32];
                    acc[t] = fmaf(val, kj, acc[t]);
                }
            }
            if (q == 0) {                   // prefetch B4: consumed from q=6
#pragma unroll
                for (int i = 0; i < 8; ++i) B4[i] = lds[sb + 32 + i];
            }
            kc = kn;
        }
        if (s == 3) {                       // tap 128 uses B4 exactly
            const float k128 = ldsK[128];
#pragma unroll
            for (int t = 0; t < 8; ++t) acc[t] = fmaf(B4[t], k128, acc[t]);
        }
    }

    // ---- transpose through LDS (window now dead) for coalesced stores ----
    __syncthreads();
#pragma unroll
    for (int i = 0; i < 8; ++i) lds[base + i] = acc[i];
    __syncthreads();
    float* __restrict__ ob = out + ((size_t)c * HN + h0) * WD + x0;
#pragma unroll
    for (int k = 0; k < 8; ++k) {
        const int r = r8 + 8 * k;
        float v = lds[r * PITCH + col64];
        if (ACC) v += ob[(size_t)r * WD + col64];
        ob[(size_t)r * WD + col64] = v;
    }
}

// ================= conv along H (axis 1), single-stage LDS =================
// Block: 512 thr = 8 waves. Tile: 64 output rows x 64 cols; lane = col,
// wave = 8-row output chunk. Full 192x64 window staged once (48.5 KB,
// pitch 64, lane-consecutive = conflict-free; 3 blocks/CU = 24 waves).
// Stores are lane-coalesced already (256 B/row).
__global__ __launch_bounds__(512, 6) void conv_h_lds(const float* __restrict__ in,
                                                     const float* __restrict__ kern,
                                                     float* __restrict__ out) {
    __shared__ float lds[192 * 64 + 132];
    float* __restrict__ ldsK = lds + 192 * 64;
    const int tid = threadIdx.x;
    const int x0  = blockIdx.x * 64;
    const int h0  = blockIdx.y * 64;
    const int c   = blockIdx.z;
    const float* __restrict__ in_c = in + (size_t)c * HN * WN + x0;

    if (tid < 132) ldsK[tid] = (tid < KN) ? kern[c * KN + tid] : 0.f;

    const int wv = tid >> 6;            // wave -> 8-row output chunk
    const int l  = tid & 63;            // lane = col
    const int baseRow = wv * 8;         // window row of output row 0 tap 0
    const int col = tid & 63;           // staging: lane-coalesced
    const int r8  = tid >> 6;           // 0..7; rows r8 + 8k, k<24

    // ---- stage the full 192 x 64 window once: rows [h0-64, h0+128) ----
    const int off = h0 - 64;
    if (off >= 0 && off + 192 <= HN) {  // interior fast path
#pragma unroll
        for (int k = 0; k < 24; ++k)
            lds[(r8 + 8 * k) * 64 + col] =
                in_c[(size_t)(off + r8 + 8 * k) * WN + col];
    } else {
#pragma unroll
        for (int k = 0; k < 24; ++k) {
            int g  = off + r8 + 8 * k;
            int gc = min(max(g, 0), HN - 1);
            float v = in_c[(size_t)gc * WN + col];
            lds[(r8 + 8 * k) * 64 + col] = (g == gc) ? v : 0.f;
        }
    }
    __syncthreads();

    float acc[8];
#pragma unroll
    for (int t = 0; t < 8; ++t) acc[t] = 0.f;

    float B0[8], B1[8], B2[8], B3[8], B4[8];
    const float4* __restrict__ k4 = (const float4*)ldsK;
#pragma unroll
    for (int s = 0; s < 4; ++s) {
        const int sr = baseRow + 32 * s;
#pragma unroll
        for (int i = 0; i < 8; ++i) B0[i] = lds[(sr + i) * 64 + l];
#pragma unroll
        for (int i = 0; i < 8; ++i) B1[i] = lds[(sr + 8 + i) * 64 + l];
#pragma unroll
        for (int i = 0; i < 8; ++i) B2[i] = lds[(sr + 16 + i) * 64 + l];
#pragma unroll
        for (int i = 0; i < 8; ++i) B3[i] = lds[(sr + 24 + i) * 64 + l];
        float4 kc = k4[8 * s];
#pragma unroll
        for (int q = 0; q < 8; ++q) {       // 4 taps per q, 32 taps/stage
            float4 kn = (q < 7) ? k4[8 * s + q + 1] : kc;
#pragma unroll
            for (int u = 0; u < 4; ++u) {
                const int up = 4 * q + u;
                const float kj = (u == 0) ? kc.x : (u == 1) ? kc.y
                               : (u == 2) ? kc.z : kc.w;
#pragma unroll
                for (int t = 0; t < 8; ++t) {
                    const int e = up + t;
                    const float val = (e < 8)  ? B0[e]
                                    : (e < 16) ? B1[e - 8]
                                    : (e < 24) ? B2[e - 16]
                                    : (e < 32) ? B3[e - 24] : B4[e - 32];
                    acc[t] = fmaf(val, kj, acc[t]);
                }
            }
            if (q == 0) {                   // prefetch B4: consumed from q=6
#pragma unroll
                for (int i = 0; i < 8; ++i) B4[i] = lds[(sr + 32 + i) * 64 + l];
            }
            kc = kn;
        }
        if (s == 3) {                       // tap 128 uses B4 exactly
            const float k128 = ldsK[128];
#pragma unroll
            for (int t = 0; t < 8; ++t) acc[t] = fmaf(B4[t], k128, acc[t]);
        }
    }

    float* __restrict__ ob = out + ((size_t)c * HN + h0 + baseRow) * WN + x0 + l;
#pragma unroll
    for (int t = 0; t < 8; ++t) ob[(size_t)t * WN] = acc[t];
}

// ---------------- forward rotate via LDS tile ----------------
// 64x64 output tile per block; rotated source bbox (<=91x91, +-1 ulp margin)
// staged COALESCED into LDS, zero-extended (bilinear w/ per-corner validity
// == bilinear on zero-extended plane, value-identical). Gather = 2x
// ds_read2_b32 per output; lane addr stride ~83 dwords -> bank stride 19/20
// mod 32, near conflict-free. Writes: wave = one 64-wide row, coalesced.
__global__ __launch_bounds__(256) void rot_fwd_lds(const float* __restrict__ Cin,
                                                   float* __restrict__ out,
                                                   float ca, float sa) {
    __shared__ float tile[BBR * BBP];
    const int j0 = blockIdx.x * 64;
    const int i0 = blockIdx.y * 64;
    const int c  = blockIdx.z;
    const float cc = (SN - 1) * 0.5f;               // 127.5
    // bbox of sample positions: affine in (i,j) -> extremes at tile corners
    const float yA = (float)i0 - cc, yB = (float)(i0 + 63) - cc;
    const float xA = (float)j0 - cc, xB = (float)(j0 + 63) - cc;
    const float syAA = ca * yA + sa * xA + cc, syAB = ca * yA + sa * xB + cc;
    const float syBA = ca * yB + sa * xA + cc, syBB = ca * yB + sa * xB + cc;
    const float sxAA = -sa * yA + ca * xA + cc, sxAB = -sa * yA + ca * xB + cc;
    const float sxBA = -sa * yB + ca * xA + cc, sxBB = -sa * yB + ca * xB + cc;
    const int ybase = (int)floorf(fminf(fminf(syAA, syAB), fminf(syBA, syBB))) - 1;
    const int xbase = (int)floorf(fminf(fminf(sxAA, sxAB), fminf(sxBA, sxBB))) - 1;

    const float* __restrict__ base = Cin + (size_t)c * HN * WN;
    for (int t = threadIdx.x; t < BBR * BBP; t += 256) {
        const int r  = t / BBP;
        const int q  = t - r * BBP;
        const int gy = ybase + r;           // padded-space row == C row
        const int gx = xbase + q - PADN;    // col into C (implicit zero pad)
        float v = 0.f;
        if ((unsigned)gy < (unsigned)HN && (unsigned)gx < (unsigned)WN)
            v = base[(size_t)gy * WN + gx];
        tile[t] = v;
    }
    __syncthreads();

    const int l  = threadIdx.x & 63;        // col within tile (lane)
    const int r0 = threadIdx.x >> 6;        // wave -> row phase
    const int j  = j0 + l;
    const float xx = (float)j - cc;
    float* __restrict__ ocol = out + (size_t)c * SN * SN + j;
#pragma unroll
    for (int t = 0; t < 16; ++t) {
        const int i = i0 + r0 + 4 * t;
        const float yy = (float)i - cc;
        const float sy = ca * yy + sa * xx + cc;
        const float sx = -sa * yy + ca * xx + cc;
        const float y0f = floorf(sy), x0f = floorf(sx);
        const float fy = sy - y0f, fx = sx - x0f;
        const int ly = (int)y0f - ybase;
        const int lx = (int)x0f - xbase;
        const float* p = tile + ly * BBP + lx;
        const float v00 = p[0], v01 = p[1], v10 = p[BBP], v11 = p[BBP + 1];
        ocol[(size_t)i * SN] = (1.f - fy) * ((1.f - fx) * v00 + fx * v01)
                             + fy * ((1.f - fx) * v10 + fx * v11);
    }
}

// ---------------- inverse rotate via LDS tile (+ optional fused finalize) ----
// Same structure; source = U (256x256, zero-extended), output 64x64 tile of
// the cropped 256x192 image. FINAL: dst = C (d_out) in place,
// out = (C + acc + tail2) / norm[c]  -- replaces final_k.
template <bool FINAL>
__global__ __launch_bounds__(256) void rot_bwd_lds(const float* __restrict__ U,
                                                   float* __restrict__ dst,
                                                   const float* __restrict__ accIn,
                                                   const float* __restrict__ norm,
                                                   float ca, float sa) {
    __shared__ float tile[BBR * BBP];
    const int x0 = blockIdx.x * 64;
    const int i0 = blockIdx.y * 64;
    const int c  = blockIdx.z;
    const float cc = (SN - 1) * 0.5f;
    const float yA = (float)i0 - cc, yB = (float)(i0 + 63) - cc;
    const float xA = (float)(x0 + PADN) - cc, xB = (float)(x0 + PADN + 63) - cc;
    const float syAA = ca * yA + sa * xA + cc, syAB = ca * yA + sa * xB + cc;
    const float syBA = ca * yB + sa * xA + cc, syBB = ca * yB + sa * xB + cc;
    const float sxAA = -sa * yA + ca * xA + cc, sxAB = -sa * yA + ca * xB + cc;
    const float sxBA = -sa * yB + ca * xA + cc, sxBB = -sa * yB + ca * xB + cc;
    const int ybase = (int)floorf(fminf(fminf(syAA, syAB), fminf(syBA, syBB))) - 1;
    const int xbase = (int)floorf(fminf(fminf(sxAA, sxAB), fminf(sxBA, sxBB))) - 1;

    const float* __restrict__ base = U + (size_t)c * SN * SN;
    for (int t = threadIdx.x; t < BBR * BBP; t += 256) {
        const int r  = t / BBP;
        const int q  = t - r * BBP;
        const int gy = ybase + r;
        const int gx = xbase + q;
        float v = 0.f;
        if ((unsigned)gy < (unsigned)SN && (unsigned)gx < (unsigned)SN)
            v = base[(size_t)gy * SN + gx];
        tile[t] = v;
    }
    __syncthreads();

    const int l  = threadIdx.x & 63;
    const int r0 = threadIdx.x >> 6;
    const int xc = x0 + l;
    const float xx = (float)(xc + PADN) - cc;
    float inv = 0.f;
    if constexpr (FINAL) inv = 1.f / norm[c];
#pragma unroll
    for (int t = 0; t < 16; ++t) {
        const int i = i0 + r0 + 4 * t;
        const float yy = (float)i - cc;
        const float sy = ca * yy + sa * xx + cc;
        const float sx = -sa * yy + ca * xx + cc;
        const float y0f = floorf(sy), x0f = floorf(sx);
        const float fy = sy - y0f, fx = sx - x0f;
        const int ly = (int)y0f - ybase;
        const int lx = (int)x0f - xbase;
        const float* p = tile + ly * BBP + lx;
        const float v00 = p[0], v01 = p[1], v10 = p[BBP], v11 = p[BBP + 1];
        const float val = (1.f - fy) * ((1.f - fx) * v00 + fx * v01)
                        + fy * ((1.f - fx) * v10 + fx * v11);
        const size_t idx = ((size_t)c * HN + i) * WN + xc;
        if constexpr (FINAL) {
            dst[idx] = (dst[idx] + accIn[idx] + val) * inv;
        } else {
            dst[idx] += val;
        }
    }
}

extern "C" void kernel_launch(void* const* d_in, const int* in_sizes, int n_in,
                              void* d_out, int out_size, void* d_ws, size_t ws_size,
                              hipStream_t stream) {
    const float* x    = (const float*)d_in[0];
    const float* kg   = (const float*)d_in[1];
    const float* kw   = (const float*)d_in[2];
    const float* kiso = (const float*)d_in[3];
    const float* norm = (const float*)d_in[4];

    float* C = (float*)d_out;                 // 256*256*192 floats
    float* ws = (float*)d_ws;
    const size_t IMG = (size_t)CN * HN * WN;  // 12,582,912
    const size_t PSQ = (size_t)CN * SN * SN;  // 16,777,216
    float* B   = ws;                          // IMG
    float* acc = ws + IMG;                    // IMG
    float* T   = ws + 2 * IMG;                // PSQ
    float* U   = T + PSQ;                     // PSQ

    const dim3 blk256(256);
    const dim3 blk512(512);
    const dim3 convHGrid(WN / 64, HN / 64, CN);
    const dim3 convW192Grid(WN / 64, HN / 64, CN);
    const dim3 convW256Grid(SN / 64, HN / 64, CN);
    const dim3 rotFGrid(SN / 64, SN / 64, CN);   // 4 x 4 x 256
    const dim3 rotBGrid(WN / 64, HN / 64, CN);   // 3 x 4 x 256

    // 1-2: gaussian separable conv -> C (d_out)
    conv_h_lds<<<convHGrid, blk512, 0, stream>>>(x, kg, B);
    conv_w_lds<WN, false><<<convW192Grid, blk512, 0, stream>>>(B, kg, C);
    // 3-4: iso separable conv -> acc
    conv_h_lds<<<convHGrid, blk512, 0, stream>>>(C, kiso, B);
    conv_w_lds<WN, false><<<convW192Grid, blk512, 0, stream>>>(B, kiso, acc);
    // 5: i=0 tail term (identity rotation): acc += conv_w(C, kw)
    conv_w_lds<WN, true><<<convW192Grid, blk512, 0, stream>>>(C, kw, acc);
    // 6-11: i=1,2 tail terms
    const double a1 = 60.0 * M_PI / 180.0, a2 = 120.0 * M_PI / 180.0;
    const float c1 = (float)cos(a1), s1 = (float)sin(a1);
    const float c2 = (float)cos(a2), s2 = (float)sin(a2);

    rot_fwd_lds<<<rotFGrid, blk256, 0, stream>>>(C, T, c1, s1);
    conv_w_lds<SN, false><<<convW256Grid, blk512, 0, stream>>>(T, kw, U);
    rot_bwd_lds<false><<<rotBGrid, blk256, 0, stream>>>(U, acc, nullptr, nullptr, c1, -s1);

    rot_fwd_lds<<<rotFGrid, blk256, 0, stream>>>(C, T, c2, s2);
    conv_w_lds<SN, false><<<convW256Grid, blk512, 0, stream>>>(T, kw, U);
    // 12 fused: out = (C + acc + tail2) / norm[c]
    rot_bwd_lds<true><<<rotBGrid, blk256, 0, stream>>>(U, C, acc, norm, c2, -s2);

    (void)in_sizes; (void)n_in; (void)out_size; (void)ws_size;
}